// Round 3
// baseline (1069.122 us; speedup 1.0000x reference)
//
#include <hip/hip_runtime.h>
#include <hip/hip_fp16.h>
#include <stdint.h>

#define D 256
#define CHSH 13   // column-chunk shift: 8192 nodes/chunk = 4.2 MB bf16 rows ~ per-XCD L2

typedef __attribute__((ext_vector_type(8))) short short8;
typedef __attribute__((ext_vector_type(4))) float floatx4;

__device__ __forceinline__ ushort f2bf(float f) {
    union { float f; uint32_t u; } v; v.f = f;
    uint32_t u = v.u;
    u += 0x7fffu + ((u >> 16) & 1u);   // RNE
    return (ushort)(u >> 16);
}
__device__ __forceinline__ float bf2f(ushort h) {
    union { uint32_t u; float f; } v; v.u = ((uint32_t)h) << 16;
    return v.f;
}

// ---------------- two-phase bucketed CSR build ----------------
// coarse bucket = row>>6 (64 rows); fine key = (row&63)*NCH + (col>>CHSH).
// Phase A partitions edges into ~1563 coarse streams (full-line writes);
// phase B counting-sorts each bucket in LDS and writes csr into its own
// contiguous (L2-resident) range + emits rowp.

// LDS-aggregated coarse histogram; block covers 32768 edges
__global__ __launch_bounds__(1024) void k_hist0(const int* __restrict__ er,
                                                int* __restrict__ cc, int E, int NB) {
    __shared__ int h[2048];
    int t = threadIdx.x;
    h[t] = 0; h[t + 1024] = 0;
    __syncthreads();
    int base = blockIdx.x * 32768;
    for (int i = t; i < 32768; i += 1024) {
        int e = base + i;
        if (e < E) atomicAdd(&h[er[e] >> 6], 1);
    }
    __syncthreads();
    int v = h[t];
    if (t < NB && v) atomicAdd(&cc[t], v);
    v = h[t + 1024];
    if (t + 1024 < NB && v) atomicAdd(&cc[t + 1024], v);
}

// exclusive scan of cc[0..NB) -> cbase (and cursor copy); NB <= 2048
__global__ __launch_bounds__(1024) void k_scan0(const int* __restrict__ cc,
                                                int* __restrict__ cbase, int* __restrict__ cursor,
                                                int* __restrict__ rowp, int NB, int E, int n) {
    __shared__ int s[1024];
    int t = threadIdx.x;
    int p0 = (2 * t < NB) ? cc[2 * t] : 0;
    int p1 = (2 * t + 1 < NB) ? cc[2 * t + 1] : 0;
    int v = p0 + p1;
    s[t] = v; __syncthreads();
    for (int off = 1; off < 1024; off <<= 1) {
        int x = (t >= off) ? s[t - off] : 0;
        __syncthreads();
        s[t] += x;
        __syncthreads();
    }
    int excl = s[t] - v;
    if (2 * t < NB)     { cbase[2 * t] = excl;          cursor[2 * t] = excl; }
    if (2 * t + 1 < NB) { cbase[2 * t + 1] = excl + p0; cursor[2 * t + 1] = excl + p0; }
    if (t == 0) { cbase[NB] = E; rowp[n] = E; }
}

// phase A: partition into coarse buckets; rec = (fine key, packed col|val)
__global__ void k_scatterA(const int* __restrict__ er, const int* __restrict__ ec,
                           const float* __restrict__ ev, int* __restrict__ cursor,
                           uint2* __restrict__ rec, int E, int NCH) {
    int e = blockIdx.x * 256 + threadIdx.x;
    if (e >= E) return;
    int r = er[e], c = ec[e];
    int p = atomicAdd(&cursor[r >> 6], 1);
    ushort hb = __half_as_ushort(__float2half_rn(ev[e]));   // val in [0,1/32): sign bit free
    rec[p] = make_uint2((unsigned)((r & 63) * NCH + (c >> CHSH)),
                        ((uint32_t)c << 15) | (uint32_t)hb);
}

// phase B: per-bucket LDS counting sort -> csr + rowp
__global__ __launch_bounds__(256) void k_binB(const uint2* __restrict__ rec,
                                              const int* __restrict__ cbase,
                                              uint32_t* __restrict__ csr,
                                              int* __restrict__ rowp, int NCH, int n) {
    __shared__ int h[1024];
    __shared__ int ws[256];
    int t = threadIdx.x, b = blockIdx.x;
    int base = cbase[b], cnt = cbase[b + 1] - base;
    h[t] = 0; h[t + 256] = 0; h[t + 512] = 0; h[t + 768] = 0;
    __syncthreads();
    for (int i = t; i < cnt; i += 256) atomicAdd(&h[rec[base + i].x], 1);
    __syncthreads();
    int c0 = h[4 * t], c1 = h[4 * t + 1], c2 = h[4 * t + 2], c3 = h[4 * t + 3];
    int s = c0 + c1 + c2 + c3;
    ws[t] = s; __syncthreads();
    for (int off = 1; off < 256; off <<= 1) {
        int x = (t >= off) ? ws[t - off] : 0;
        __syncthreads();
        ws[t] += x;
        __syncthreads();
    }
    int run = ws[t] - s;   // exclusive
    h[4 * t] = run; run += c0;
    h[4 * t + 1] = run; run += c1;
    h[4 * t + 2] = run; run += c2;
    h[4 * t + 3] = run;
    __syncthreads();
    if (t < 64) {
        int grow = b * 64 + t;
        if (grow < n) rowp[grow] = base + h[t * NCH];
    }
    __syncthreads();
    for (int i = t; i < cnt; i += 256) {
        uint2 r = rec[base + i];
        int pos = base + atomicAdd(&h[r.x], 1);
        csr[pos] = r.y;
    }
}

// ---------------- conversions (ego + W fused) ----------------
__global__ void k_cvt(const float4* __restrict__ ego, ushort4* __restrict__ ego_bf,
                      const float4* __restrict__ W1, const float4* __restrict__ W2,
                      ushort4* __restrict__ W1b, ushort4* __restrict__ W2b, int n4) {
    int i = blockIdx.x * 256 + threadIdx.x;
    const float4* src;
    ushort4* dst;
    if (i < n4) { src = ego + i; dst = ego_bf + i; }
    else {
        int j = i - n4;
        if (j >= 32768) return;
        int k = j & 16383;
        src = ((j < 16384) ? W1 : W2) + k;
        dst = ((j < 16384) ? W1b : W2b) + k;
    }
    float4 f = *src;
    ushort4 u;
    u.x = f2bf(f.x); u.y = f2bf(f.y); u.z = f2bf(f.z); u.w = f2bf(f.w);
    *dst = u;
}

// ---------------- SpMM + bi-interaction inputs ----------------
// one wave per node; lane owns 4 consecutive features; edge loop unrolled x8
__global__ void k_spmm(const ushort* __restrict__ ego_bf, const int* __restrict__ rowp,
                       const uint32_t* __restrict__ csr,
                       ushort* __restrict__ X1, ushort* __restrict__ X2, int n) {
    int gtid = blockIdx.x * 256 + threadIdx.x;
    int node = gtid >> 6;
    int lane = gtid & 63;
    if (node >= n) return;
    int beg = rowp[node], end = rowp[node + 1];
    int d0 = lane * 4;
    float a0 = 0.f, a1 = 0.f, a2 = 0.f, a3 = 0.f;
    int e = beg;
    for (; e + 8 <= end; e += 8) {
        uint32_t w[8];
#pragma unroll
        for (int j = 0; j < 8; ++j) w[j] = csr[e + j];
        ushort4 u[8];
#pragma unroll
        for (int j = 0; j < 8; ++j)
            u[j] = *(const ushort4*)(ego_bf + (size_t)(w[j] >> 15) * D + d0);
#pragma unroll
        for (int j = 0; j < 8; ++j) {
            float v = __half2float(__ushort_as_half((ushort)(w[j] & 0x7fff)));
            a0 += v * bf2f(u[j].x);
            a1 += v * bf2f(u[j].y);
            a2 += v * bf2f(u[j].z);
            a3 += v * bf2f(u[j].w);
        }
    }
    for (; e < end; ++e) {
        uint32_t w = csr[e];
        float v = __half2float(__ushort_as_half((ushort)(w & 0x7fff)));
        ushort4 u = *(const ushort4*)(ego_bf + (size_t)(w >> 15) * D + d0);
        a0 += v * bf2f(u.x);
        a1 += v * bf2f(u.y);
        a2 += v * bf2f(u.z);
        a3 += v * bf2f(u.w);
    }
    ushort4 eg = *(const ushort4*)(ego_bf + (size_t)node * D + d0);
    float e0 = bf2f(eg.x), e1 = bf2f(eg.y), e2 = bf2f(eg.z), e3 = bf2f(eg.w);
    ushort4 o1, o2;
    o1.x = f2bf(e0 + a0); o2.x = f2bf(e0 * a0);
    o1.y = f2bf(e1 + a1); o2.y = f2bf(e1 * a1);
    o1.z = f2bf(e2 + a2); o2.z = f2bf(e2 * a2);
    o1.w = f2bf(e3 + a3); o2.w = f2bf(e3 * a3);
    *(ushort4*)(X1 + (size_t)node * D + d0) = o1;
    *(ushort4*)(X2 + (size_t)node * D + d0) = o2;
}

// ---------------- fused dual GEMM + epilogue ----------------
__global__ __launch_bounds__(256) void k_gemm(
        const ushort* __restrict__ X1, const ushort* __restrict__ X2,
        const ushort* __restrict__ W1b, const ushort* __restrict__ W2b,
        const float* __restrict__ b1, const float* __restrict__ b2,
        float* __restrict__ out, int n) {
    int lane = threadIdx.x & 63;
    int w = threadIdx.x >> 6;
    int l16 = lane & 15, quad = lane >> 4;
    int row0 = blockIdx.x * 64;
    int colw = w * 64;

    floatx4 acc1[4][4], acc2[4][4];
#pragma unroll
    for (int i = 0; i < 4; ++i)
#pragma unroll
        for (int j = 0; j < 4; ++j) { acc1[i][j] = (floatx4)0.f; acc2[i][j] = (floatx4)0.f; }

    for (int kk = 0; kk < D; kk += 32) {
        short8 a[4], b[4];
#pragma unroll
        for (int mt = 0; mt < 4; ++mt)
            a[mt] = *(const short8*)(X1 + (size_t)(row0 + mt * 16 + l16) * D + kk + quad * 8);
#pragma unroll
        for (int nt = 0; nt < 4; ++nt)
            b[nt] = *(const short8*)(W1b + (size_t)(colw + nt * 16 + l16) * D + kk + quad * 8);
#pragma unroll
        for (int mt = 0; mt < 4; ++mt)
#pragma unroll
            for (int nt = 0; nt < 4; ++nt)
                acc1[mt][nt] = __builtin_amdgcn_mfma_f32_16x16x32_bf16(a[mt], b[nt], acc1[mt][nt], 0, 0, 0);
    }
    for (int kk = 0; kk < D; kk += 32) {
        short8 a[4], b[4];
#pragma unroll
        for (int mt = 0; mt < 4; ++mt)
            a[mt] = *(const short8*)(X2 + (size_t)(row0 + mt * 16 + l16) * D + kk + quad * 8);
#pragma unroll
        for (int nt = 0; nt < 4; ++nt)
            b[nt] = *(const short8*)(W2b + (size_t)(colw + nt * 16 + l16) * D + kk + quad * 8);
#pragma unroll
        for (int mt = 0; mt < 4; ++mt)
#pragma unroll
            for (int nt = 0; nt < 4; ++nt)
                acc2[mt][nt] = __builtin_amdgcn_mfma_f32_16x16x32_bf16(a[mt], b[nt], acc2[mt][nt], 0, 0, 0);
    }

#pragma unroll
    for (int nt = 0; nt < 4; ++nt) {
        int col = colw + nt * 16 + l16;
        float bb1 = b1[col], bb2 = b2[col];
#pragma unroll
        for (int mt = 0; mt < 4; ++mt) {
            int row = row0 + mt * 16 + quad * 4;
#pragma unroll
            for (int r = 0; r < 4; ++r) {
                if (row + r < n) {
                    float v1 = acc1[mt][nt][r] + bb1;
                    v1 = v1 > 0.f ? v1 : 0.01f * v1;
                    float v2 = acc2[mt][nt][r] + bb2;
                    v2 = v2 > 0.f ? v2 : 0.01f * v2;
                    out[(size_t)(row + r) * D + col] = v1 + v2;
                }
            }
        }
    }
}

extern "C" void kernel_launch(void* const* d_in, const int* in_sizes, int n_in,
                              void* d_out, int out_size, void* d_ws, size_t ws_size,
                              hipStream_t stream) {
    const float* ego   = (const float*)d_in[0];
    const float* evals = (const float*)d_in[1];
    const float* W1    = (const float*)d_in[2];
    const float* b1    = (const float*)d_in[3];
    const float* W2    = (const float*)d_in[4];
    const float* b2    = (const float*)d_in[5];
    const int* erows   = (const int*)d_in[6];
    const int* ecols   = (const int*)d_in[7];
    float* out = (float*)d_out;

    int n = in_sizes[0] / D;          // 100000
    int E = in_sizes[1];              // 3200000
    int npad = (n + 63) & ~63;        // 100032
    int NCH = (n + (1 << CHSH) - 1) >> CHSH;   // 13 column chunks
    int NB = (n + 63) >> 6;           // 1563 coarse buckets

    char* p = (char*)d_ws;
    auto alloc = [&](size_t bytes) {
        char* q = p;
        p += (bytes + 511) & ~(size_t)511;
        return q;
    };
    ushort* ego_bf = (ushort*)alloc((size_t)n * D * 2);      // 51.2 MB
    ushort* X1     = (ushort*)alloc((size_t)npad * D * 2);   // 51.2 MB
    ushort* X2     = (ushort*)alloc((size_t)npad * D * 2);   // 51.2 MB
    ushort* W1b    = (ushort*)alloc((size_t)D * D * 2);
    ushort* W2b    = (ushort*)alloc((size_t)D * D * 2);
    uint32_t* csr  = (uint32_t*)alloc((size_t)E * 4);        // 12.8 MB
    int* cc        = (int*)alloc((size_t)(NB + 1) * 4);
    int* cbase     = (int*)alloc((size_t)(NB + 1) * 4);
    int* cursor    = (int*)alloc((size_t)NB * 4);
    int* rowp      = (int*)alloc((size_t)(n + 1) * 4);
    uint2* recA    = (uint2*)X2;   // phase-A records alias X2 (consumed before spmm writes X2)

    hipMemsetAsync(cc, 0, (size_t)(NB + 1) * 4, stream);
    k_hist0<<<(E + 32767) / 32768, 1024, 0, stream>>>(erows, cc, E, NB);
    k_scan0<<<1, 1024, 0, stream>>>(cc, cbase, cursor, rowp, NB, E, n);
    k_scatterA<<<(E + 255) / 256, 256, 0, stream>>>(erows, ecols, evals, cursor, recA, E, NCH);
    k_binB<<<NB, 256, 0, stream>>>(recA, cbase, csr, rowp, NCH, n);

    int n4 = n * (D / 4);
    k_cvt<<<(n4 + 32768 + 255) / 256, 256, 0, stream>>>((const float4*)ego, (ushort4*)ego_bf,
                                                        (const float4*)W1, (const float4*)W2,
                                                        (ushort4*)W1b, (ushort4*)W2b, n4);

    k_spmm<<<(n * 64 + 255) / 256, 256, 0, stream>>>(ego_bf, rowp, csr, X1, X2, n);

    k_gemm<<<npad / 64, 256, 0, stream>>>(X1, X2, W1b, W2b, b1, b2, out, n);
}